// Round 1
// baseline (4049.318 us; speedup 1.0000x reference)
//
#include <hip/hip_runtime.h>
#include <cstddef>
#include <cstdint>

// Problem dims: B=16, L=256, V=32000, E=256, H=256
// ws layout (bytes):
//   [0, 65536)        h exchange: [2 dir][2 parity][16 b][256 j] f32
//   [65536, 65664)    barrier counters: cnt[0] (fwd) at +0, cnt[16] (bwd) at +64B
//   [65792, +4MB)     x embedding rows: [4096 m][256 e] f32, m = t*16 + b
//   [.., +33.5MB)     G = x@W_ih^T + b, both dirs: [4096 m][2048 n], n = dir*1024 + gate*256 + j
#define HX_OFF   0
#define CNT_OFF  65536
#define MS_BYTES 65792
#define X_OFF    65792
#define G_OFF    (X_OFF + 4096 * 256 * 4)

#define NWG 32   // workgroups per direction
#define JW  8    // h-columns owned per workgroup

// ---------------- Phase 1: one-hot scan + embedding gather ----------------
__global__ __launch_bounds__(256) void k_embed(const float* __restrict__ seq,
                                               const float* __restrict__ emb,
                                               float* __restrict__ x) {
  const int m = blockIdx.x;          // m = t*16 + b
  const int t = m >> 4, b = m & 15;
  const float* row = seq + (size_t)(b * 256 + t) * 32000;
  __shared__ int sid;
  if (threadIdx.x == 0) sid = 0;
  __syncthreads();
  for (int base = threadIdx.x * 4; base < 32000; base += 1024) {
    const float4 v = *reinterpret_cast<const float4*>(row + base);
    if (v.x != 0.f) sid = base;
    if (v.y != 0.f) sid = base + 1;
    if (v.z != 0.f) sid = base + 2;
    if (v.w != 0.f) sid = base + 3;
  }
  __syncthreads();
  x[(size_t)m * 256 + threadIdx.x] = emb[(size_t)sid * 256 + threadIdx.x];
}

// ---------------- Phase 2: G = x @ [W_ih_f|W_ih_b]^T + bias ----------------
__global__ __launch_bounds__(256) void k_gemm(const float* __restrict__ x,
                                              const float* __restrict__ Wf,
                                              const float* __restrict__ Wb,
                                              const float* __restrict__ bf,
                                              const float* __restrict__ bb,
                                              float* __restrict__ Gm) {
  __shared__ float As[16][72];
  __shared__ float Bs[16][72];
  const int m0 = (blockIdx.x >> 5) * 64;
  const int n0 = (blockIdx.x & 31) * 64;
  const int tid = threadIdx.x;
  const int tx = tid & 15, ty = tid >> 4;
  float acc[4][4] = {};
  const int lr = tid >> 2;           // 0..63
  const int lc = (tid & 3) * 4;      // 0,4,8,12
  const int n = n0 + lr;
  const float* wp = (n < 1024) ? (Wf + (size_t)n * 256) : (Wb + (size_t)(n - 1024) * 256);
  const float* ap = x + (size_t)(m0 + lr) * 256;
  for (int k0 = 0; k0 < 256; k0 += 16) {
    const float4 a = *reinterpret_cast<const float4*>(ap + k0 + lc);
    const float4 w = *reinterpret_cast<const float4*>(wp + k0 + lc);
    As[lc + 0][lr] = a.x; As[lc + 1][lr] = a.y; As[lc + 2][lr] = a.z; As[lc + 3][lr] = a.w;
    Bs[lc + 0][lr] = w.x; Bs[lc + 1][lr] = w.y; Bs[lc + 2][lr] = w.z; Bs[lc + 3][lr] = w.w;
    __syncthreads();
#pragma unroll
    for (int k = 0; k < 16; ++k) {
      const float4 av = *reinterpret_cast<const float4*>(&As[k][ty * 4]);
      const float4 bv = *reinterpret_cast<const float4*>(&Bs[k][tx * 4]);
      const float aa[4] = {av.x, av.y, av.z, av.w};
      const float bw[4] = {bv.x, bv.y, bv.z, bv.w};
#pragma unroll
      for (int i = 0; i < 4; ++i)
#pragma unroll
        for (int j = 0; j < 4; ++j) acc[i][j] = fmaf(aa[i], bw[j], acc[i][j]);
    }
    __syncthreads();
  }
#pragma unroll
  for (int j = 0; j < 4; ++j) {
    const int nn = n0 + tx * 4 + j;
    const float bias = (nn < 1024) ? bf[nn] : bb[nn - 1024];
#pragma unroll
    for (int i = 0; i < 4; ++i)
      Gm[(size_t)(m0 + ty * 4 + i) * 2048 + nn] = acc[i][j] + bias;
  }
}

// ---------------- Phase 3: bidirectional LSTM scan ----------------
// Grid: 64 WGs = 2 dirs x 32 WGs. WG (d, widx) owns j in [widx*8, widx*8+8) for all b.
// Thread map (compute): tid = ks*32 + g*8 + jl ; ks in [0,8) -> k-chunk of 32, g gate, jl j-local.
// W_hh rows live in VGPRs (32 f32/thread). h exchanged via global parity buffer + spin barrier.
__device__ __forceinline__ int hidx(int b, int k) {
  // swizzled LDS layout: per-b row of 296 f32; 32-wide k-chunks at stride 36
  return b * 296 + (k >> 5) * 36 + (k & 31);
}

__global__ __launch_bounds__(256) void k_scan(const float* __restrict__ Whf,
                                              const float* __restrict__ Whb,
                                              const int* __restrict__ lengths,
                                              const float* __restrict__ Gm,
                                              float* hx,
                                              unsigned int* cnt,
                                              float* __restrict__ out) {
  const int wg = blockIdx.x;
  const int d = wg / NWG;
  const int widx = wg - d * NWG;
  const int j0 = widx * JW;
  const float* Wh = d ? Whb : Whf;
  unsigned int* mycnt = cnt + d * 16;
  const int tid = threadIdx.x;
  const int jl = tid & 7;
  const int g = (tid >> 3) & 3;
  const int ks = tid >> 5;

  // resident W_hh fragment: rows (g*256 + j0 + jl), k in [ks*32, ks*32+32)
  float wreg[32];
  {
    const float* wr = Wh + (size_t)(g * 256 + j0 + jl) * 256 + ks * 32;
#pragma unroll
    for (int u = 0; u < 8; ++u) {
      const float4 wv = *reinterpret_cast<const float4*>(wr + u * 4);
      wreg[u * 4 + 0] = wv.x; wreg[u * 4 + 1] = wv.y;
      wreg[u * 4 + 2] = wv.z; wreg[u * 4 + 3] = wv.w;
    }
  }

  const bool isfin = tid < 128;          // final-phase threads: (fb, fj)
  const int fb = (tid >> 3) & 15;
  const int fj = tid & 7;
  float c_st = 0.f, h_st = 0.f;
  const int mylen = isfin ? lengths[fb] : 0;

  __shared__ float h_lds[16 * 296];
  __shared__ float part[4][4][8][20];    // [wave][gate][jl][b]

  float* hxd = hx + d * 2 * 4096;        // per-dir exchange: [2 parity][16][256]

  for (int s = 0; s < 256; ++s) {
    const int t = d ? (255 - s) : s;
    // prefetch input-gate preactivations (no dependency on h) before the spin
    float gp0 = 0.f, gp1 = 0.f, gp2 = 0.f, gp3 = 0.f;
    if (isfin) {
      const float* gp = Gm + (size_t)(t * 16 + fb) * 2048 + d * 1024 + j0 + fj;
      gp0 = gp[0]; gp1 = gp[256]; gp2 = gp[512]; gp3 = gp[768];
    }
    // barrier: wait until all NWG blocks of this dir finished step s-1
    if (s > 0) {
      if (tid == 0) {
        const unsigned target = (unsigned)(NWG * s);
        while (__hip_atomic_load(mycnt, __ATOMIC_ACQUIRE, __HIP_MEMORY_SCOPE_AGENT) < target)
          __builtin_amdgcn_s_sleep(1);
      }
      __syncthreads();
    }
    // load h_prev (parity s&1) into LDS, device-coherent
    {
      float* hsrc = hxd + (s & 1) * 4096;
      const int b_ = tid >> 4;
      const int k0 = (tid & 15) * 16;
#pragma unroll
      for (int u = 0; u < 4; ++u) {
        const int k = k0 + u * 4;
        const float v0 = __hip_atomic_load(hsrc + b_ * 256 + k + 0, __ATOMIC_RELAXED, __HIP_MEMORY_SCOPE_AGENT);
        const float v1 = __hip_atomic_load(hsrc + b_ * 256 + k + 1, __ATOMIC_RELAXED, __HIP_MEMORY_SCOPE_AGENT);
        const float v2 = __hip_atomic_load(hsrc + b_ * 256 + k + 2, __ATOMIC_RELAXED, __HIP_MEMORY_SCOPE_AGENT);
        const float v3 = __hip_atomic_load(hsrc + b_ * 256 + k + 3, __ATOMIC_RELAXED, __HIP_MEMORY_SCOPE_AGENT);
        *reinterpret_cast<float4*>(&h_lds[hidx(b_, k)]) = make_float4(v0, v1, v2, v3);
      }
    }
    __syncthreads();

    // recurrent MAC: acc[b] = dot(W_row(g, j0+jl)[ks*32..+32), h[b][ks*32..+32))
    float acc[16];
#pragma unroll
    for (int b_ = 0; b_ < 16; ++b_) {
      const float* hp = &h_lds[b_ * 296 + ks * 36];
      float a0 = 0.f, a1 = 0.f;
#pragma unroll
      for (int u = 0; u < 4; ++u) {
        const float4 h0 = *reinterpret_cast<const float4*>(hp + u * 8);
        const float4 h1 = *reinterpret_cast<const float4*>(hp + u * 8 + 4);
        a0 = fmaf(wreg[u * 8 + 0], h0.x, a0); a0 = fmaf(wreg[u * 8 + 1], h0.y, a0);
        a0 = fmaf(wreg[u * 8 + 2], h0.z, a0); a0 = fmaf(wreg[u * 8 + 3], h0.w, a0);
        a1 = fmaf(wreg[u * 8 + 4], h1.x, a1); a1 = fmaf(wreg[u * 8 + 5], h1.y, a1);
        a1 = fmaf(wreg[u * 8 + 6], h1.z, a1); a1 = fmaf(wreg[u * 8 + 7], h1.w, a1);
      }
      acc[b_] = a0 + a1;
    }
    // reduce over ks: lane bit 5 pairs in-wave, then 4 wave-partials via LDS
#pragma unroll
    for (int b_ = 0; b_ < 16; ++b_) acc[b_] += __shfl_xor(acc[b_], 32, 64);
    const int wv = tid >> 6;
    const int lane = tid & 63;
    if (lane < 32) {
      const int lg = lane >> 3, lj = lane & 7;
#pragma unroll
      for (int u = 0; u < 4; ++u)
        *reinterpret_cast<float4*>(&part[wv][lg][lj][u * 4]) =
            make_float4(acc[u * 4 + 0], acc[u * 4 + 1], acc[u * 4 + 2], acc[u * 4 + 3]);
    }
    __syncthreads();

    if (isfin) {
      float gi = gp0, gf = gp1, gg = gp2, go = gp3;
#pragma unroll
      for (int w2 = 0; w2 < 4; ++w2) {
        gi += part[w2][0][fj][fb];
        gf += part[w2][1][fj][fb];
        gg += part[w2][2][fj][fb];
        go += part[w2][3][fj][fb];
      }
      const float ig = 1.f / (1.f + __expf(-gi));
      const float fg = 1.f / (1.f + __expf(-gf));
      const float gt = tanhf(gg);
      const float og = 1.f / (1.f + __expf(-go));
      const float cn = fmaf(fg, c_st, ig * gt);
      const float hn = og * tanhf(cn);
      const bool msk = t < mylen;
      c_st = msk ? cn : c_st;
      h_st = msk ? hn : h_st;
      out[((size_t)fb * 256 + t) * 512 + d * 256 + j0 + fj] = msk ? hn : 0.f;
      __hip_atomic_store(hxd + ((s + 1) & 1) * 4096 + fb * 256 + j0 + fj, h_st,
                         __ATOMIC_RELAXED, __HIP_MEMORY_SCOPE_AGENT);
    }
    if (s < 255) {
      __threadfence();
      __syncthreads();
      if (tid == 0)
        __hip_atomic_fetch_add(mycnt, 1u, __ATOMIC_RELEASE, __HIP_MEMORY_SCOPE_AGENT);
    }
  }
}

extern "C" void kernel_launch(void* const* d_in, const int* in_sizes, int n_in,
                              void* d_out, int out_size, void* d_ws, size_t ws_size,
                              hipStream_t stream) {
  const float* seq = (const float*)d_in[0];
  const float* emb = (const float*)d_in[1];
  const float* Wif = (const float*)d_in[2];
  const float* Whf = (const float*)d_in[3];
  const float* bf  = (const float*)d_in[4];
  const float* Wib = (const float*)d_in[5];
  const float* Whb = (const float*)d_in[6];
  const float* bbv = (const float*)d_in[7];
  const int* lengths = (const int*)d_in[8];
  float* out = (float*)d_out;
  char* ws = (char*)d_ws;
  float* x  = (float*)(ws + X_OFF);
  float* Gm = (float*)(ws + G_OFF);
  float* hx = (float*)(ws + HX_OFF);
  unsigned int* cnt = (unsigned int*)(ws + CNT_OFF);

  // zero the h-exchange buffers + barrier counters every launch (ws is re-poisoned)
  hipMemsetAsync(d_ws, 0, MS_BYTES, stream);
  k_embed<<<dim3(4096), dim3(256), 0, stream>>>(seq, emb, x);
  k_gemm<<<dim3(2048), dim3(256), 0, stream>>>(x, Wif, Wib, bf, bbv, Gm);
  k_scan<<<dim3(64), dim3(256), 0, stream>>>(Whf, Whb, lengths, Gm, hx, cnt, out);
}

// Round 2
// 2628.189 us; speedup vs baseline: 1.5407x; 1.5407x over previous
//
#include <hip/hip_runtime.h>
#include <cstddef>
#include <cstdint>

// Problem dims: B=16, L=256, V=32000, E=256, H=256
// ws layout (bytes):
//   [0, 65536)        h exchange: [2 dir][2 parity][16 b][256 j] f32
//   [65536, 65664)    barrier counters: cnt[0] (fwd) at +0, cnt[16] (bwd) at +64B
//   [65792, +4MB)     x embedding rows: [4096 m][256 e] f32, m = t*16 + b
//   [.., +33.5MB)     G = x@W_ih^T + b, both dirs: [4096 m][2048 n], n = dir*1024 + gate*256 + j
#define HX_OFF   0
#define CNT_OFF  65536
#define MS_BYTES 65792
#define X_OFF    65792
#define G_OFF    (X_OFF + 4096 * 256 * 4)

#define NWG 32   // workgroups per direction
#define JW  8    // h-columns owned per workgroup

// ---------------- Phase 1: one-hot scan + embedding gather ----------------
__global__ __launch_bounds__(256) void k_embed(const float* __restrict__ seq,
                                               const float* __restrict__ emb,
                                               float* __restrict__ x) {
  const int m = blockIdx.x;          // m = t*16 + b
  const int t = m >> 4, b = m & 15;
  const float* row = seq + (size_t)(b * 256 + t) * 32000;
  __shared__ int sid;
  if (threadIdx.x == 0) sid = 0;
  __syncthreads();
  for (int base = threadIdx.x * 4; base < 32000; base += 1024) {
    const float4 v = *reinterpret_cast<const float4*>(row + base);
    if (v.x != 0.f) sid = base;
    if (v.y != 0.f) sid = base + 1;
    if (v.z != 0.f) sid = base + 2;
    if (v.w != 0.f) sid = base + 3;
  }
  __syncthreads();
  x[(size_t)m * 256 + threadIdx.x] = emb[(size_t)sid * 256 + threadIdx.x];
}

// ---------------- Phase 2: G = x @ [W_ih_f|W_ih_b]^T + bias ----------------
__global__ __launch_bounds__(256) void k_gemm(const float* __restrict__ x,
                                              const float* __restrict__ Wf,
                                              const float* __restrict__ Wb,
                                              const float* __restrict__ bf,
                                              const float* __restrict__ bb,
                                              float* __restrict__ Gm) {
  __shared__ float As[16][72];
  __shared__ float Bs[16][72];
  const int m0 = (blockIdx.x >> 5) * 64;
  const int n0 = (blockIdx.x & 31) * 64;
  const int tid = threadIdx.x;
  const int tx = tid & 15, ty = tid >> 4;
  float acc[4][4] = {};
  const int lr = tid >> 2;           // 0..63
  const int lc = (tid & 3) * 4;      // 0,4,8,12
  const int n = n0 + lr;
  const float* wp = (n < 1024) ? (Wf + (size_t)n * 256) : (Wb + (size_t)(n - 1024) * 256);
  const float* ap = x + (size_t)(m0 + lr) * 256;
  for (int k0 = 0; k0 < 256; k0 += 16) {
    const float4 a = *reinterpret_cast<const float4*>(ap + k0 + lc);
    const float4 w = *reinterpret_cast<const float4*>(wp + k0 + lc);
    As[lc + 0][lr] = a.x; As[lc + 1][lr] = a.y; As[lc + 2][lr] = a.z; As[lc + 3][lr] = a.w;
    Bs[lc + 0][lr] = w.x; Bs[lc + 1][lr] = w.y; Bs[lc + 2][lr] = w.z; Bs[lc + 3][lr] = w.w;
    __syncthreads();
#pragma unroll
    for (int k = 0; k < 16; ++k) {
      const float4 av = *reinterpret_cast<const float4*>(&As[k][ty * 4]);
      const float4 bv = *reinterpret_cast<const float4*>(&Bs[k][tx * 4]);
      const float aa[4] = {av.x, av.y, av.z, av.w};
      const float bw[4] = {bv.x, bv.y, bv.z, bv.w};
#pragma unroll
      for (int i = 0; i < 4; ++i)
#pragma unroll
        for (int j = 0; j < 4; ++j) acc[i][j] = fmaf(aa[i], bw[j], acc[i][j]);
    }
    __syncthreads();
  }
#pragma unroll
  for (int j = 0; j < 4; ++j) {
    const int nn = n0 + tx * 4 + j;
    const float bias = (nn < 1024) ? bf[nn] : bb[nn - 1024];
#pragma unroll
    for (int i = 0; i < 4; ++i)
      Gm[(size_t)(m0 + ty * 4 + i) * 2048 + nn] = acc[i][j] + bias;
  }
}

// ---------------- Phase 3: bidirectional LSTM scan ----------------
// Grid: 64 WGs = 2 dirs x 32 WGs. WG (d, widx) owns j in [widx*8, widx*8+8) for all b.
// Thread map (compute): tid = ks*32 + g*8 + jl ; ks in [0,8) -> k-chunk of 32, g gate, jl j-local.
// W_hh rows live in VGPRs (32 f32/thread). h exchanged via global parity buffer + spin barrier.
//
// Sync discipline (gfx950, 8 non-coherent XCD L2s): ALL cross-WG traffic uses
// agent-scope RELAXED atomics (these go to the L3 coherence point, bypassing
// the incoherent L1/L2). Release ordering is achieved by draining vmcnt
// (stores complete at L3) before the counter increment — NO acquire/release
// fences, which on gfx950 emit L2 writeback/invalidate (buffer_wbl2/inv) and
// both serialize the step AND evict the L2-resident Gm (seen as 3x HBM
// over-fetch in round 1).
__device__ __forceinline__ int hidx(int b, int k) {
  // swizzled LDS layout: per-b row of 296 f32; 32-wide k-chunks at stride 36
  return b * 296 + (k >> 5) * 36 + (k & 31);
}

__global__ __launch_bounds__(256) void k_scan(const float* __restrict__ Whf,
                                              const float* __restrict__ Whb,
                                              const int* __restrict__ lengths,
                                              const float* __restrict__ Gm,
                                              float* hx,
                                              unsigned int* cnt,
                                              float* __restrict__ out) {
  const int wg = blockIdx.x;
  const int d = wg / NWG;
  const int widx = wg - d * NWG;
  const int j0 = widx * JW;
  const float* Wh = d ? Whb : Whf;
  unsigned int* mycnt = cnt + d * 16;
  const int tid = threadIdx.x;
  const int jl = tid & 7;
  const int g = (tid >> 3) & 3;
  const int ks = tid >> 5;

  // resident W_hh fragment: rows (g*256 + j0 + jl), k in [ks*32, ks*32+32)
  float wreg[32];
  {
    const float* wr = Wh + (size_t)(g * 256 + j0 + jl) * 256 + ks * 32;
#pragma unroll
    for (int u = 0; u < 8; ++u) {
      const float4 wv = *reinterpret_cast<const float4*>(wr + u * 4);
      wreg[u * 4 + 0] = wv.x; wreg[u * 4 + 1] = wv.y;
      wreg[u * 4 + 2] = wv.z; wreg[u * 4 + 3] = wv.w;
    }
  }

  const bool isfin = tid < 128;          // final-phase threads: (fb, fj)
  const int fb = (tid >> 3) & 15;
  const int fj = tid & 7;
  float c_st = 0.f, h_st = 0.f;
  const int mylen = isfin ? lengths[fb] : 0;

  __shared__ float h_lds[16 * 296];
  __shared__ float part[4][4][8][20];    // [wave][gate][jl][b]

  float* hxd = hx + d * 2 * 4096;        // per-dir exchange: [2 parity][16][256]

  for (int s = 0; s < 256; ++s) {
    const int t = d ? (255 - s) : s;
    // prefetch input-gate preactivations (no dependency on h) before the spin
    float gp0 = 0.f, gp1 = 0.f, gp2 = 0.f, gp3 = 0.f;
    if (isfin) {
      const float* gp = Gm + (size_t)(t * 16 + fb) * 2048 + d * 1024 + j0 + fj;
      gp0 = gp[0]; gp1 = gp[256]; gp2 = gp[512]; gp3 = gp[768];
    }
    // barrier: wait until all NWG blocks of this dir finished step s-1.
    // RELAXED spin — no acquire cache-maintenance; the h loads below are
    // agent-scope themselves so they cannot read stale cache lines.
    if (s > 0) {
      if (tid == 0) {
        const unsigned target = (unsigned)(NWG * s);
        while (__hip_atomic_load(mycnt, __ATOMIC_RELAXED, __HIP_MEMORY_SCOPE_AGENT) < target)
          __builtin_amdgcn_s_sleep(1);
      }
      __syncthreads();
    }
    // load h_prev (parity s&1) into LDS, straight from L3 (agent-scope)
    {
      float* hsrc = hxd + (s & 1) * 4096;
      const int b_ = tid >> 4;
      const int k0 = (tid & 15) * 16;
#pragma unroll
      for (int u = 0; u < 4; ++u) {
        const int k = k0 + u * 4;
        const float v0 = __hip_atomic_load(hsrc + b_ * 256 + k + 0, __ATOMIC_RELAXED, __HIP_MEMORY_SCOPE_AGENT);
        const float v1 = __hip_atomic_load(hsrc + b_ * 256 + k + 1, __ATOMIC_RELAXED, __HIP_MEMORY_SCOPE_AGENT);
        const float v2 = __hip_atomic_load(hsrc + b_ * 256 + k + 2, __ATOMIC_RELAXED, __HIP_MEMORY_SCOPE_AGENT);
        const float v3 = __hip_atomic_load(hsrc + b_ * 256 + k + 3, __ATOMIC_RELAXED, __HIP_MEMORY_SCOPE_AGENT);
        *reinterpret_cast<float4*>(&h_lds[hidx(b_, k)]) = make_float4(v0, v1, v2, v3);
      }
    }
    __syncthreads();

    // recurrent MAC: acc[b] = dot(W_row(g, j0+jl)[ks*32..+32), h[b][ks*32..+32))
    float acc[16];
#pragma unroll
    for (int b_ = 0; b_ < 16; ++b_) {
      const float* hp = &h_lds[b_ * 296 + ks * 36];
      float a0 = 0.f, a1 = 0.f;
#pragma unroll
      for (int u = 0; u < 4; ++u) {
        const float4 h0 = *reinterpret_cast<const float4*>(hp + u * 8);
        const float4 h1 = *reinterpret_cast<const float4*>(hp + u * 8 + 4);
        a0 = fmaf(wreg[u * 8 + 0], h0.x, a0); a0 = fmaf(wreg[u * 8 + 1], h0.y, a0);
        a0 = fmaf(wreg[u * 8 + 2], h0.z, a0); a0 = fmaf(wreg[u * 8 + 3], h0.w, a0);
        a1 = fmaf(wreg[u * 8 + 4], h1.x, a1); a1 = fmaf(wreg[u * 8 + 5], h1.y, a1);
        a1 = fmaf(wreg[u * 8 + 6], h1.z, a1); a1 = fmaf(wreg[u * 8 + 7], h1.w, a1);
      }
      acc[b_] = a0 + a1;
    }
    // reduce over ks: lane bit 5 pairs in-wave, then 4 wave-partials via LDS
#pragma unroll
    for (int b_ = 0; b_ < 16; ++b_) acc[b_] += __shfl_xor(acc[b_], 32, 64);
    const int wv = tid >> 6;
    const int lane = tid & 63;
    if (lane < 32) {
      const int lg = lane >> 3, lj = lane & 7;
#pragma unroll
      for (int u = 0; u < 4; ++u)
        *reinterpret_cast<float4*>(&part[wv][lg][lj][u * 4]) =
            make_float4(acc[u * 4 + 0], acc[u * 4 + 1], acc[u * 4 + 2], acc[u * 4 + 3]);
    }
    __syncthreads();

    if (isfin) {
      float gi = gp0, gf = gp1, gg = gp2, go = gp3;
#pragma unroll
      for (int w2 = 0; w2 < 4; ++w2) {
        gi += part[w2][0][fj][fb];
        gf += part[w2][1][fj][fb];
        gg += part[w2][2][fj][fb];
        go += part[w2][3][fj][fb];
      }
      const float ig = 1.f / (1.f + __expf(-gi));
      const float fg = 1.f / (1.f + __expf(-gf));
      const float gt = tanhf(gg);
      const float og = 1.f / (1.f + __expf(-go));
      const float cn = fmaf(fg, c_st, ig * gt);
      const float hn = og * tanhf(cn);
      const bool msk = t < mylen;
      c_st = msk ? cn : c_st;
      h_st = msk ? hn : h_st;
      out[((size_t)fb * 256 + t) * 512 + d * 256 + j0 + fj] = msk ? hn : 0.f;
      __hip_atomic_store(hxd + ((s + 1) & 1) * 4096 + fb * 256 + j0 + fj, h_st,
                         __ATOMIC_RELAXED, __HIP_MEMORY_SCOPE_AGENT);
    }
    if (s < 255) {
      // Release without cache maintenance: drain this wave's stores to the
      // coherence point, then cross-wave barrier, then RELAXED increment.
      asm volatile("s_waitcnt vmcnt(0)" ::: "memory");
      __syncthreads();
      if (tid == 0)
        __hip_atomic_fetch_add(mycnt, 1u, __ATOMIC_RELAXED, __HIP_MEMORY_SCOPE_AGENT);
    }
  }
}

extern "C" void kernel_launch(void* const* d_in, const int* in_sizes, int n_in,
                              void* d_out, int out_size, void* d_ws, size_t ws_size,
                              hipStream_t stream) {
  const float* seq = (const float*)d_in[0];
  const float* emb = (const float*)d_in[1];
  const float* Wif = (const float*)d_in[2];
  const float* Whf = (const float*)d_in[3];
  const float* bf  = (const float*)d_in[4];
  const float* Wib = (const float*)d_in[5];
  const float* Whb = (const float*)d_in[6];
  const float* bbv = (const float*)d_in[7];
  const int* lengths = (const int*)d_in[8];
  float* out = (float*)d_out;
  char* ws = (char*)d_ws;
  float* x  = (float*)(ws + X_OFF);
  float* Gm = (float*)(ws + G_OFF);
  float* hx = (float*)(ws + HX_OFF);
  unsigned int* cnt = (unsigned int*)(ws + CNT_OFF);

  // zero the h-exchange buffers + barrier counters every launch (ws is re-poisoned)
  hipMemsetAsync(d_ws, 0, MS_BYTES, stream);
  k_embed<<<dim3(4096), dim3(256), 0, stream>>>(seq, emb, x);
  k_gemm<<<dim3(2048), dim3(256), 0, stream>>>(x, Wif, Wib, bf, bbv, Gm);
  k_scan<<<dim3(64), dim3(256), 0, stream>>>(Whf, Whb, lengths, Gm, hx, cnt, out);
}

// Round 3
// 2228.730 us; speedup vs baseline: 1.8169x; 1.1792x over previous
//
#include <hip/hip_runtime.h>
#include <cstddef>
#include <cstdint>

// Problem dims: B=16, L=256, V=32000, E=256, H=256
// ws layout (bytes):
//   [0, 65536)        h exchange: [2 dir][2 parity][16 b][256 j] f32
//   [65536, 69632)    arrival flags: [2 dir][32 wg] u32, one per 64B line
//   [131072, +4MB)    x embedding rows: [4096 m][256 e] f32, m = t*16 + b
//   [.., +33.5MB)     G = x@W_ih^T + b, both dirs: [4096 m][2048 n], n = dir*1024 + gate*256 + j
#define HX_OFF   0
#define FLG_OFF  65536
#define MS_BYTES 69632
#define X_OFF    131072
#define G_OFF    (X_OFF + 4096 * 256 * 4)

#define NWG 32   // workgroups per direction
#define JW  8    // h-columns owned per workgroup

// ---------------- Phase 1: one-hot scan + embedding gather ----------------
__global__ __launch_bounds__(256) void k_embed(const float* __restrict__ seq,
                                               const float* __restrict__ emb,
                                               float* __restrict__ x) {
  const int m = blockIdx.x;          // m = t*16 + b
  const int t = m >> 4, b = m & 15;
  const float* row = seq + (size_t)(b * 256 + t) * 32000;
  __shared__ int sid;
  if (threadIdx.x == 0) sid = 0;
  __syncthreads();
  for (int base = threadIdx.x * 4; base < 32000; base += 1024) {
    const float4 v = *reinterpret_cast<const float4*>(row + base);
    if (v.x != 0.f) sid = base;
    if (v.y != 0.f) sid = base + 1;
    if (v.z != 0.f) sid = base + 2;
    if (v.w != 0.f) sid = base + 3;
  }
  __syncthreads();
  x[(size_t)m * 256 + threadIdx.x] = emb[(size_t)sid * 256 + threadIdx.x];
}

// ---------------- Phase 2: G = x @ [W_ih_f|W_ih_b]^T + bias ----------------
__global__ __launch_bounds__(256) void k_gemm(const float* __restrict__ x,
                                              const float* __restrict__ Wf,
                                              const float* __restrict__ Wb,
                                              const float* __restrict__ bf,
                                              const float* __restrict__ bb,
                                              float* __restrict__ Gm) {
  __shared__ float As[16][72];
  __shared__ float Bs[16][72];
  const int m0 = (blockIdx.x >> 5) * 64;
  const int n0 = (blockIdx.x & 31) * 64;
  const int tid = threadIdx.x;
  const int tx = tid & 15, ty = tid >> 4;
  float acc[4][4] = {};
  const int lr = tid >> 2;           // 0..63
  const int lc = (tid & 3) * 4;      // 0,4,8,12
  const int n = n0 + lr;
  const float* wp = (n < 1024) ? (Wf + (size_t)n * 256) : (Wb + (size_t)(n - 1024) * 256);
  const float* ap = x + (size_t)(m0 + lr) * 256;
  for (int k0 = 0; k0 < 256; k0 += 16) {
    const float4 a = *reinterpret_cast<const float4*>(ap + k0 + lc);
    const float4 w = *reinterpret_cast<const float4*>(wp + k0 + lc);
    As[lc + 0][lr] = a.x; As[lc + 1][lr] = a.y; As[lc + 2][lr] = a.z; As[lc + 3][lr] = a.w;
    Bs[lc + 0][lr] = w.x; Bs[lc + 1][lr] = w.y; Bs[lc + 2][lr] = w.z; Bs[lc + 3][lr] = w.w;
    __syncthreads();
#pragma unroll
    for (int k = 0; k < 16; ++k) {
      const float4 av = *reinterpret_cast<const float4*>(&As[k][ty * 4]);
      const float4 bv = *reinterpret_cast<const float4*>(&Bs[k][tx * 4]);
      const float aa[4] = {av.x, av.y, av.z, av.w};
      const float bw[4] = {bv.x, bv.y, bv.z, bv.w};
#pragma unroll
      for (int i = 0; i < 4; ++i)
#pragma unroll
        for (int j = 0; j < 4; ++j) acc[i][j] = fmaf(aa[i], bw[j], acc[i][j]);
    }
    __syncthreads();
  }
#pragma unroll
  for (int j = 0; j < 4; ++j) {
    const int nn = n0 + tx * 4 + j;
    const float bias = (nn < 1024) ? bf[nn] : bb[nn - 1024];
#pragma unroll
    for (int i = 0; i < 4; ++i)
      Gm[(size_t)(m0 + ty * 4 + i) * 2048 + nn] = acc[i][j] + bias;
  }
}

// ---------------- Phase 3: bidirectional LSTM scan ----------------
// Grid: 64 WGs = 2 dirs x 32 WGs. WG (d, widx) owns j in [widx*8, widx*8+8) for all b.
// Sync: per-WG arrival flags on separate 64B lines (NO shared counter — a
// contended counter serializes 32 increments behind 64 spinning waves at L3,
// ~5us/step in round 2). Producers: h stores (agent atomics -> L3) -> vmcnt(0)
// -> syncthreads -> flag[my]=s+1 (own line, uncontended). Consumers: each wave
// independently reads all 32 flags in one pipelined burst (lane&31) + __all.
__device__ __forceinline__ int hidx(int b, int k) {
  // swizzled LDS layout: per-b row of 296 f32; 32-wide k-chunks at stride 36
  return b * 296 + (k >> 5) * 36 + (k & 31);
}

__global__ __launch_bounds__(256) void k_scan(const float* __restrict__ Whf,
                                              const float* __restrict__ Whb,
                                              const int* __restrict__ lengths,
                                              const float* __restrict__ Gm,
                                              float* hx,
                                              unsigned int* flags,
                                              float* __restrict__ out) {
  const int wg = blockIdx.x;
  const int d = wg / NWG;
  const int widx = wg - d * NWG;
  const int j0 = widx * JW;
  const float* Wh = d ? Whb : Whf;
  const int tid = threadIdx.x;
  const int jl = tid & 7;
  const int g = (tid >> 3) & 3;
  const int ks = tid >> 5;

  // resident W_hh fragment: rows (g*256 + j0 + jl), k in [ks*32, ks*32+32)
  float wreg[32];
  {
    const float* wr = Wh + (size_t)(g * 256 + j0 + jl) * 256 + ks * 32;
#pragma unroll
    for (int u = 0; u < 8; ++u) {
      const float4 wv = *reinterpret_cast<const float4*>(wr + u * 4);
      wreg[u * 4 + 0] = wv.x; wreg[u * 4 + 1] = wv.y;
      wreg[u * 4 + 2] = wv.z; wreg[u * 4 + 3] = wv.w;
    }
  }

  const bool isfin = tid < 128;          // final-phase threads: (fb, fj)
  const int fb = (tid >> 3) & 15;
  const int fj = tid & 7;
  float c_st = 0.f, h_st = 0.f;
  const int mylen = isfin ? lengths[fb] : 0;

  __shared__ float h_lds[16 * 296];
  __shared__ float part[4][4][8][20];    // [wave][gate][jl][b]

  float* hxd = hx + d * 2 * 4096;        // per-dir exchange: [2 parity][16][256]
  unsigned int* myflag = flags + (d * NWG + widx) * 16;
  unsigned int* spinflag = flags + (d * NWG + (tid & 31)) * 16;

  for (int s = 0; s < 256; ++s) {
    const int t = d ? (255 - s) : s;
    // prefetch input-gate preactivations (no dependency on h) before the spin
    float gp0 = 0.f, gp1 = 0.f, gp2 = 0.f, gp3 = 0.f;
    if (isfin) {
      const float* gp = Gm + (size_t)(t * 16 + fb) * 2048 + d * 1024 + j0 + fj;
      gp0 = gp[0]; gp1 = gp[256]; gp2 = gp[512]; gp3 = gp[768];
    }
    // barrier: each wave independently waits until all 32 WGs of this dir
    // posted step s (64 lanes read 32 distinct flag lines, one burst + __all)
    if (s > 0) {
      const unsigned target = (unsigned)s;
      unsigned v = __hip_atomic_load(spinflag, __ATOMIC_RELAXED, __HIP_MEMORY_SCOPE_AGENT);
      while (!__all(v >= target)) {
        __builtin_amdgcn_s_sleep(1);
        v = __hip_atomic_load(spinflag, __ATOMIC_RELAXED, __HIP_MEMORY_SCOPE_AGENT);
      }
    }
    // load h_prev (parity s&1) into LDS, straight from the coherence point
    {
      const unsigned long long* hsrc =
          reinterpret_cast<const unsigned long long*>(hxd + (s & 1) * 4096);
      const int b_ = tid >> 4;
      const int k0 = (tid & 15) * 16;
#pragma unroll
      for (int u = 0; u < 4; ++u) {
        const int k = k0 + u * 4;
        const int qi = (b_ * 256 + k) >> 1;
        const unsigned long long q0 = __hip_atomic_load(hsrc + qi, __ATOMIC_RELAXED, __HIP_MEMORY_SCOPE_AGENT);
        const unsigned long long q1 = __hip_atomic_load(hsrc + qi + 1, __ATOMIC_RELAXED, __HIP_MEMORY_SCOPE_AGENT);
        const float2 f0 = __builtin_bit_cast(float2, q0);
        const float2 f1 = __builtin_bit_cast(float2, q1);
        *reinterpret_cast<float4*>(&h_lds[hidx(b_, k)]) = make_float4(f0.x, f0.y, f1.x, f1.y);
      }
    }
    __syncthreads();

    // recurrent MAC: acc[b] = dot(W_row(g, j0+jl)[ks*32..+32), h[b][ks*32..+32))
    float acc[16];
#pragma unroll
    for (int b_ = 0; b_ < 16; ++b_) {
      const float* hp = &h_lds[b_ * 296 + ks * 36];
      float a0 = 0.f, a1 = 0.f;
#pragma unroll
      for (int u = 0; u < 4; ++u) {
        const float4 h0 = *reinterpret_cast<const float4*>(hp + u * 8);
        const float4 h1 = *reinterpret_cast<const float4*>(hp + u * 8 + 4);
        a0 = fmaf(wreg[u * 8 + 0], h0.x, a0); a0 = fmaf(wreg[u * 8 + 1], h0.y, a0);
        a0 = fmaf(wreg[u * 8 + 2], h0.z, a0); a0 = fmaf(wreg[u * 8 + 3], h0.w, a0);
        a1 = fmaf(wreg[u * 8 + 4], h1.x, a1); a1 = fmaf(wreg[u * 8 + 5], h1.y, a1);
        a1 = fmaf(wreg[u * 8 + 6], h1.z, a1); a1 = fmaf(wreg[u * 8 + 7], h1.w, a1);
      }
      acc[b_] = a0 + a1;
    }
    // reduce over ks: lane bit 5 pairs in-wave, then 4 wave-partials via LDS
#pragma unroll
    for (int b_ = 0; b_ < 16; ++b_) acc[b_] += __shfl_xor(acc[b_], 32, 64);
    const int wv = tid >> 6;
    const int lane = tid & 63;
    if (lane < 32) {
      const int lg = lane >> 3, lj = lane & 7;
#pragma unroll
      for (int u = 0; u < 4; ++u)
        *reinterpret_cast<float4*>(&part[wv][lg][lj][u * 4]) =
            make_float4(acc[u * 4 + 0], acc[u * 4 + 1], acc[u * 4 + 2], acc[u * 4 + 3]);
    }
    __syncthreads();

    bool msk = false;
    if (isfin) {
      float gi = gp0, gf = gp1, gg = gp2, go = gp3;
#pragma unroll
      for (int w2 = 0; w2 < 4; ++w2) {
        gi += part[w2][0][fj][fb];
        gf += part[w2][1][fj][fb];
        gg += part[w2][2][fj][fb];
        go += part[w2][3][fj][fb];
      }
      const float ig = 1.f / (1.f + __expf(-gi));
      const float fg = 1.f / (1.f + __expf(-gf));
      const float gt = tanhf(gg);
      const float og = 1.f / (1.f + __expf(-go));
      const float cn = fmaf(fg, c_st, ig * gt);
      const float hn = og * tanhf(cn);
      msk = t < mylen;
      c_st = msk ? cn : c_st;
      h_st = msk ? hn : h_st;
    }
    if (s < 255) {
      // release: h store -> drain to coherence point -> all waves done -> flag
      if (isfin)
        __hip_atomic_store(hxd + ((s + 1) & 1) * 4096 + fb * 256 + j0 + fj, h_st,
                           __ATOMIC_RELAXED, __HIP_MEMORY_SCOPE_AGENT);
      asm volatile("s_waitcnt vmcnt(0)" ::: "memory");
      __syncthreads();
      if (tid == 0)
        __hip_atomic_store(myflag, (unsigned)(s + 1), __ATOMIC_RELAXED, __HIP_MEMORY_SCOPE_AGENT);
    }
    // output store off the release critical path
    if (isfin)
      out[((size_t)fb * 256 + t) * 512 + d * 256 + j0 + fj] = msk ? h_st : 0.f;
  }
}

extern "C" void kernel_launch(void* const* d_in, const int* in_sizes, int n_in,
                              void* d_out, int out_size, void* d_ws, size_t ws_size,
                              hipStream_t stream) {
  const float* seq = (const float*)d_in[0];
  const float* emb = (const float*)d_in[1];
  const float* Wif = (const float*)d_in[2];
  const float* Whf = (const float*)d_in[3];
  const float* bf  = (const float*)d_in[4];
  const float* Wib = (const float*)d_in[5];
  const float* Whb = (const float*)d_in[6];
  const float* bbv = (const float*)d_in[7];
  const int* lengths = (const int*)d_in[8];
  float* out = (float*)d_out;
  char* ws = (char*)d_ws;
  float* x  = (float*)(ws + X_OFF);
  float* Gm = (float*)(ws + G_OFF);
  float* hx = (float*)(ws + HX_OFF);
  unsigned int* flags = (unsigned int*)(ws + FLG_OFF);

  // zero the h-exchange buffers + arrival flags every launch (ws is re-poisoned)
  hipMemsetAsync(d_ws, 0, MS_BYTES, stream);
  k_embed<<<dim3(4096), dim3(256), 0, stream>>>(seq, emb, x);
  k_gemm<<<dim3(2048), dim3(256), 0, stream>>>(x, Wif, Wib, bf, bbv, Gm);
  k_scan<<<dim3(64), dim3(256), 0, stream>>>(Whf, Whb, lengths, Gm, hx, flags, out);
}

// Round 4
// 1833.867 us; speedup vs baseline: 2.2081x; 1.2153x over previous
//
#include <hip/hip_runtime.h>
#include <cstddef>
#include <cstdint>

// Problem dims: B=16, L=256, V=32000, E=256, H=256
// ws layout (bytes):
//   [0, 32768)     h exchange: [2 dir][2 parity][16 b][256 j] bf16(ushort)
//   [32768, 33280) arrival flags: [2 dir][4 wg] u32, one per 64B line
//   [65536, +4MB)  x embedding rows: [4096 m][256 e] f32, m = t*16 + b
//   [.., +33.5MB)  G = x@W_ih^T + b, both dirs: [4096 m][2048 n], n = dir*1024 + gate*256 + j
#define HX_OFF   0
#define FLG_OFF  32768
#define MS_BYTES 33280
#define X_OFF    65536
#define G_OFF    (X_OFF + 4096 * 256 * 4)

typedef __attribute__((ext_vector_type(8))) short short8;
typedef __attribute__((ext_vector_type(4))) float f32x4;
typedef __attribute__((ext_vector_type(2))) unsigned long long ulong2v;

__device__ __forceinline__ unsigned short f2bf(float f) {
  unsigned u = __builtin_bit_cast(unsigned, f);
  u = (u + 0x7fffu + ((u >> 16) & 1u)) >> 16;   // round-to-nearest-even
  return (unsigned short)u;
}

// ---------------- Phase 1: one-hot scan + embedding gather ----------------
__global__ __launch_bounds__(256) void k_embed(const float* __restrict__ seq,
                                               const float* __restrict__ emb,
                                               float* __restrict__ x) {
  const int m = blockIdx.x;          // m = t*16 + b
  const int t = m >> 4, b = m & 15;
  const float* row = seq + (size_t)(b * 256 + t) * 32000;
  __shared__ int sid;
  if (threadIdx.x == 0) sid = 0;
  __syncthreads();
  for (int base = threadIdx.x * 4; base < 32000; base += 1024) {
    const float4 v = *reinterpret_cast<const float4*>(row + base);
    if (v.x != 0.f) sid = base;
    if (v.y != 0.f) sid = base + 1;
    if (v.z != 0.f) sid = base + 2;
    if (v.w != 0.f) sid = base + 3;
  }
  __syncthreads();
  x[(size_t)m * 256 + threadIdx.x] = emb[(size_t)sid * 256 + threadIdx.x];
}

// ---------------- Phase 2: G = x @ [W_ih_f|W_ih_b]^T + bias ----------------
// 128x128 tile, BK=8, 256 threads, 8x8 per thread (f32 VALU).
__global__ __launch_bounds__(256) void k_gemm(const float* __restrict__ x,
                                              const float* __restrict__ Wf,
                                              const float* __restrict__ Wb,
                                              const float* __restrict__ bf,
                                              const float* __restrict__ bb,
                                              float* __restrict__ Gm) {
  __shared__ float As[8][128];
  __shared__ float Bs[8][128];
  const int tid = threadIdx.x;
  const int m0 = (blockIdx.x >> 4) * 128;   // 32 m-tiles
  const int n0 = (blockIdx.x & 15) * 128;   // 16 n-tiles
  const int lm = tid >> 1;                  // 0..127
  const int lk = (tid & 1) * 4;             // 0 or 4
  const int nrow = n0 + lm;
  const float* wrow = (nrow < 1024) ? (Wf + (size_t)nrow * 256)
                                    : (Wb + (size_t)(nrow - 1024) * 256);
  const float* arow = x + (size_t)(m0 + lm) * 256;
  const int tm = (tid >> 4) * 8;
  const int tn = (tid & 15) * 8;
  float acc[8][8] = {};
  for (int k0 = 0; k0 < 256; k0 += 8) {
    const float4 av = *reinterpret_cast<const float4*>(arow + k0 + lk);
    const float4 wv = *reinterpret_cast<const float4*>(wrow + k0 + lk);
    __syncthreads();
    As[lk + 0][lm] = av.x; As[lk + 1][lm] = av.y; As[lk + 2][lm] = av.z; As[lk + 3][lm] = av.w;
    Bs[lk + 0][lm] = wv.x; Bs[lk + 1][lm] = wv.y; Bs[lk + 2][lm] = wv.z; Bs[lk + 3][lm] = wv.w;
    __syncthreads();
#pragma unroll
    for (int k = 0; k < 8; ++k) {
      float a[8], b[8];
      *reinterpret_cast<float4*>(&a[0]) = *reinterpret_cast<const float4*>(&As[k][tm]);
      *reinterpret_cast<float4*>(&a[4]) = *reinterpret_cast<const float4*>(&As[k][tm + 4]);
      *reinterpret_cast<float4*>(&b[0]) = *reinterpret_cast<const float4*>(&Bs[k][tn]);
      *reinterpret_cast<float4*>(&b[4]) = *reinterpret_cast<const float4*>(&Bs[k][tn + 4]);
#pragma unroll
      for (int i = 0; i < 8; ++i)
#pragma unroll
        for (int j = 0; j < 8; ++j) acc[i][j] = fmaf(a[i], b[j], acc[i][j]);
    }
  }
  float bj[8];
#pragma unroll
  for (int j = 0; j < 8; ++j) {
    const int nn = n0 + tn + j;
    bj[j] = (nn < 1024) ? bf[nn] : bb[nn - 1024];
  }
#pragma unroll
  for (int i = 0; i < 8; ++i) {
    float4 o0, o1;
    o0.x = acc[i][0] + bj[0]; o0.y = acc[i][1] + bj[1]; o0.z = acc[i][2] + bj[2]; o0.w = acc[i][3] + bj[3];
    o1.x = acc[i][4] + bj[4]; o1.y = acc[i][5] + bj[5]; o1.z = acc[i][6] + bj[6]; o1.w = acc[i][7] + bj[7];
    float* op = Gm + (size_t)(m0 + tm + i) * 2048 + n0 + tn;
    *reinterpret_cast<float4*>(op) = o0;
    *reinterpret_cast<float4*>(op + 4) = o1;
  }
}

// ---------------- Phase 3: bidirectional LSTM scan (MFMA) ----------------
// Grid: 8 WGs = 2 dirs x 4 WGs x 256 thr (4 waves). WG (d,widx) owns j in
// [widx*64, +64); wave wv owns j-block [j0+wv*16, +16) x all 4 gates.
// W_hh resident in VGPRs as bf16 B-fragments (128 VGPR/thread).
// Per step: G preact -> acc (C-in), spin on 4 flags, load h bf16 A-frags
// from L3 (agent 8B atomics), 32 MFMAs, activations (lane owns j + 4 b,
// all gates local), LDS transpose, 8B agent store, vmcnt drain, flag.
__global__ __launch_bounds__(256, 1) void k_scan(const float* __restrict__ Whf,
                                                 const float* __restrict__ Whb,
                                                 const int* __restrict__ lengths,
                                                 const float* __restrict__ Gm,
                                                 unsigned short* hx,
                                                 unsigned int* flags,
                                                 float* __restrict__ out) {
  const int wg = blockIdx.x;
  const int d = wg >> 2;
  const int widx = wg & 3;
  const int j0 = widx * 64;
  const float* Wh = d ? Whb : Whf;
  const int tid = threadIdx.x;
  const int wv = tid >> 6;
  const int l = tid & 63;
  const int lr = l & 15;            // fragment row: b (A/C) or n (B)
  const int kg = l >> 4;            // k-group (8 contiguous k)
  const int jrel = wv * 16 + lr;
  const int j = j0 + jrel;

  // resident W_hh B-fragments: wfrag[g][ks] = W[g*256+j][ks*32 + kg*8 .. +8]
  short8 wfrag[4][8];
#pragma unroll
  for (int g = 0; g < 4; ++g) {
#pragma unroll
    for (int ks = 0; ks < 8; ++ks) {
      const float* wp = Wh + (size_t)(g * 256 + j) * 256 + ks * 32 + kg * 8;
      const float4 w0 = *reinterpret_cast<const float4*>(wp);
      const float4 w1 = *reinterpret_cast<const float4*>(wp + 4);
      short8 wv8;
      wv8[0] = (short)f2bf(w0.x); wv8[1] = (short)f2bf(w0.y);
      wv8[2] = (short)f2bf(w0.z); wv8[3] = (short)f2bf(w0.w);
      wv8[4] = (short)f2bf(w1.x); wv8[5] = (short)f2bf(w1.y);
      wv8[6] = (short)f2bf(w1.z); wv8[7] = (short)f2bf(w1.w);
      wfrag[g][ks] = wv8;
    }
  }

  int len4[4];
#pragma unroll
  for (int r = 0; r < 4; ++r) len4[r] = lengths[kg * 4 + r];

  float c_st[4] = {0.f, 0.f, 0.f, 0.f}, h_st[4] = {0.f, 0.f, 0.f, 0.f};

  __shared__ unsigned short h_stage[16][64];

  unsigned short* hxd = hx + d * 2 * 4096;     // [2 parity][16][256] bf16
  unsigned int* myflag = flags + (d * 4 + widx) * 16;
  const unsigned int* spinflag = flags + (d * 4 + (l & 3)) * 16;

  for (int s = 0; s < 256; ++s) {
    const int t = d ? (255 - s) : s;
    // G preactivations as MFMA C-in (plain cached loads, issued pre-spin)
    f32x4 acc[4];
    {
      const float* gp = Gm + (size_t)(t * 16 + kg * 4) * 2048 + d * 1024 + j;
#pragma unroll
      for (int g = 0; g < 4; ++g) {
#pragma unroll
        for (int r = 0; r < 4; ++r)
          acc[g][r] = gp[(size_t)r * 2048 + g * 256];
      }
    }
    // spin: all 4 WGs of this dir finished step s-1 (64 lanes cover 4 flags)
    if (s > 0) {
      unsigned v = __hip_atomic_load(spinflag, __ATOMIC_RELAXED, __HIP_MEMORY_SCOPE_AGENT);
      while (!__all(v >= (unsigned)s)) {
        __builtin_amdgcn_s_sleep(1);
        v = __hip_atomic_load(spinflag, __ATOMIC_RELAXED, __HIP_MEMORY_SCOPE_AGENT);
      }
    }
    // h_prev A-fragments straight from the coherence point (parity s&1)
    short8 afrag[8];
    {
      const unsigned long long* hq =
          reinterpret_cast<const unsigned long long*>(hxd + (s & 1) * 4096);
      const int base = lr * 64 + kg * 2;   // u64 units
#pragma unroll
      for (int ks = 0; ks < 8; ++ks) {
        const unsigned long long q0 = __hip_atomic_load(hq + base + ks * 8, __ATOMIC_RELAXED, __HIP_MEMORY_SCOPE_AGENT);
        const unsigned long long q1 = __hip_atomic_load(hq + base + ks * 8 + 1, __ATOMIC_RELAXED, __HIP_MEMORY_SCOPE_AGENT);
        ulong2v q; q.x = q0; q.y = q1;
        afrag[ks] = __builtin_bit_cast(short8, q);
      }
    }
    // recurrent GEMM: acc[g] += h_prev x W_hh[g]^T
#pragma unroll
    for (int ks = 0; ks < 8; ++ks) {
#pragma unroll
      for (int g = 0; g < 4; ++g)
        acc[g] = __builtin_amdgcn_mfma_f32_16x16x32_bf16(afrag[ks], wfrag[g][ks], acc[g], 0, 0, 0);
    }
    // activations + state update; lane owns (j, b = kg*4 + r)
    float hout[4];
#pragma unroll
    for (int r = 0; r < 4; ++r) {
      const float gi = acc[0][r], gf = acc[1][r], gg = acc[2][r], go = acc[3][r];
      const float ig = 1.f / (1.f + __expf(-gi));
      const float fg = 1.f / (1.f + __expf(-gf));
      const float gt = tanhf(gg);
      const float og = 1.f / (1.f + __expf(-go));
      const float cn = fmaf(fg, c_st[r], ig * gt);
      const float hn = og * tanhf(cn);
      const bool msk = t < len4[r];
      c_st[r] = msk ? cn : c_st[r];
      h_st[r] = msk ? hn : h_st[r];
      hout[r] = msk ? hn : 0.f;
    }
    if (s < 255) {
      // transpose via LDS, then wide 8B agent stores to parity (s+1)&1
#pragma unroll
      for (int r = 0; r < 4; ++r) h_stage[kg * 4 + r][jrel] = f2bf(h_st[r]);
      __syncthreads();
      {
        const int b_ = tid >> 4, jq = (tid & 15) * 4;
        const unsigned long long v =
            *reinterpret_cast<const unsigned long long*>(&h_stage[b_][jq]);
        unsigned long long* dq =
            reinterpret_cast<unsigned long long*>(hxd + ((s + 1) & 1) * 4096);
        __hip_atomic_store(dq + b_ * 64 + (j0 + jq) / 4, v,
                           __ATOMIC_RELAXED, __HIP_MEMORY_SCOPE_AGENT);
      }
      asm volatile("s_waitcnt vmcnt(0)" ::: "memory");
      __syncthreads();
      if (tid == 0)
        __hip_atomic_store(myflag, (unsigned)(s + 1), __ATOMIC_RELAXED, __HIP_MEMORY_SCOPE_AGENT);
    }
    // output store (off the release critical path)
    {
      float* op = out + ((size_t)(kg * 4) * 256 + t) * 512 + d * 256 + j;
#pragma unroll
      for (int r = 0; r < 4; ++r) op[(size_t)r * 256 * 512] = hout[r];
    }
  }
}

extern "C" void kernel_launch(void* const* d_in, const int* in_sizes, int n_in,
                              void* d_out, int out_size, void* d_ws, size_t ws_size,
                              hipStream_t stream) {
  const float* seq = (const float*)d_in[0];
  const float* emb = (const float*)d_in[1];
  const float* Wif = (const float*)d_in[2];
  const float* Whf = (const float*)d_in[3];
  const float* bf  = (const float*)d_in[4];
  const float* Wib = (const float*)d_in[5];
  const float* Whb = (const float*)d_in[6];
  const float* bbv = (const float*)d_in[7];
  const int* lengths = (const int*)d_in[8];
  float* out = (float*)d_out;
  char* ws = (char*)d_ws;
  float* x  = (float*)(ws + X_OFF);
  float* Gm = (float*)(ws + G_OFF);
  unsigned short* hx = (unsigned short*)(ws + HX_OFF);
  unsigned int* flags = (unsigned int*)(ws + FLG_OFF);

  // zero the h-exchange buffers + arrival flags every launch (ws is re-poisoned)
  hipMemsetAsync(d_ws, 0, MS_BYTES, stream);
  k_embed<<<dim3(4096), dim3(256), 0, stream>>>(seq, emb, x);
  k_gemm<<<dim3(512), dim3(256), 0, stream>>>(x, Wif, Wib, bf, bbv, Gm);
  k_scan<<<dim3(8), dim3(256), 0, stream>>>(Whf, Whb, lengths, Gm, hx, flags, out);
}